// Round 20
// baseline (94.794 us; speedup 1.0000x reference)
//
#include <hip/hip_runtime.h>
#include <hip/hip_bf16.h>

typedef __attribute__((ext_vector_type(4))) float f32x4;
typedef __attribute__((ext_vector_type(8))) short short8;
typedef unsigned short u16;
typedef unsigned int u32;

__device__ __forceinline__ u16 f2bf(float f) {
    u32 u = __float_as_uint(f);
    u32 r = (u + 0x7fffu + ((u >> 16) & 1u)) >> 16;
    return (u16)r;
}
__device__ __forceinline__ u32 pack2bf(float a, float b) {
    __hip_bfloat162 w = __float22bfloat162_rn(float2{a, b});
    return *(u32*)&w;
}
__device__ __forceinline__ void stage16(const u16* gsrc, u16* ldsdst) {
    __builtin_amdgcn_global_load_lds((const __attribute__((address_space(1))) void*)gsrc,
                                     (__attribute__((address_space(3))) void*)ldsdst, 16, 0, 0);
}

// ---------- prep: weight transposes only (x conversion fused into QKV GEMM) ----------
__global__ __launch_bounds__(256) void prep(const float* __restrict__ Wa,
                                            const float* __restrict__ Wp,
                                            u16* __restrict__ wat, u16* __restrict__ wpt) {
    __shared__ float tile[64][65];
    int blk = blockIdx.x;
    const float* W;
    u16* Wt;
    int N, bx, by;
    if (blk < 432) {
        W = Wa; Wt = wat; N = 2304; bx = blk % 36; by = blk / 36;
    } else {
        int i = blk - 432;
        W = Wp; Wt = wpt; N = 768; bx = i % 12; by = i / 12;
    }
    int n0 = bx * 64, k0 = by * 64;
    int c = threadIdx.x & 63, r0 = threadIdx.x >> 6;
#pragma unroll
    for (int i = 0; i < 16; ++i) {
        int r = r0 * 16 + i;
        tile[r][c] = W[(size_t)(k0 + r) * N + n0 + c];
    }
    __syncthreads();
#pragma unroll
    for (int i = 0; i < 16; ++i) {
        int r = r0 * 16 + i;
        Wt[(size_t)(n0 + r) * 768 + k0 + c] = f2bf(tile[c][r]);
    }
}

// ---------- bf16 GEMM: BK=64 single-buffer, XOR-swizzled LDS, tileable BN ----------
// MODE 0 (QKV, 128x192, grid 768 = 3/CU): A comes DIRECTLY from fp32 x —
// reg-staged (linear coalesced float4 loads -> cvt_pk -> swizzled ds_write_b128;
// write slot chunk^(row&7) matches the read-side XOR). B via global_load_lds
// with pre-swizzled source (r12: conflicts = 0). MODE 1 (proj, 64x128): both
// operands bf16 via global_load_lds. Epilogue: >=32B-contiguous stores.
template <int MODE, int WM, int WN, int WPE>
__global__ __launch_bounds__(256, WPE) void gemmT(const float* __restrict__ Af,
                                                  const u16* __restrict__ Abf,
                                                  const u16* __restrict__ Bt,
                                                  u16* __restrict__ q, u16* __restrict__ kk,
                                                  u16* __restrict__ v, float* __restrict__ outf,
                                                  int nby) {
    const int K = 768;
    const int BM = 2 * WM;
    const int BN = 2 * WN;
    const int NBF = WN / 16;
    __shared__ __align__(16) u16 As[BM * 64];
    __shared__ __align__(16) u16 Bs[BN * 64];
    int nwg = gridDim.x;
    int bid = blockIdx.x;
    int wgid = (bid & 7) * (nwg >> 3) + (bid >> 3);  // XCD-contiguous
    int mb = wgid / nby, nb = wgid % nby;
    int m0 = mb * BM, n0 = nb * BN;
    int tid = threadIdx.x;
    int wave = tid >> 6, lane = tid & 63;
    int lo = lane & 15, hi = lane >> 4;
    int wm = (wave >> 1) * WM, wn = (wave & 1) * WN;
    int srow = lane >> 3;            // 0..7 within 8-row stage chunk
    int schunk = (lane & 7) ^ srow;  // pre-swizzled source chunk (row&7 == srow)
    int sw0 = (hi ^ (lo & 7)) * 8;        // ds_read swizzle, k-chunk 0
    int sw1 = ((4 + hi) ^ (lo & 7)) * 8;  // k-chunk 1
    f32x4 acc[WM / 16][NBF] = {};
    const u16* Ab = Abf + (size_t)(m0 + (BM / 4) * wave + srow) * K + schunk * 8;
    const u16* Bb = Bt + (size_t)(n0 + (BN / 4) * wave + srow) * K + schunk * 8;
    u16* ldsA = &As[((BM / 4) * wave) * 64];
    u16* ldsB = &Bs[((BN / 4) * wave) * 64];

    for (int k0 = 0; k0 < K; k0 += 64) {
        if constexpr (MODE == 0) {
            // reg-stage A from fp32: linear global (256B runs), swizzled ds_write
#pragma unroll
            for (int c = 0; c < BM / 32; ++c) {
                int row = 32 * wave + 8 * c + srow;
                const float* src = Af + (size_t)(m0 + row) * K + k0 + (lane & 7) * 8;
                float4 v0 = *(const float4*)src;
                float4 v1 = *(const float4*)(src + 4);
                short8 w;
                u32* wp = (u32*)&w;
                wp[0] = pack2bf(v0.x, v0.y);
                wp[1] = pack2bf(v0.z, v0.w);
                wp[2] = pack2bf(v1.x, v1.y);
                wp[3] = pack2bf(v1.z, v1.w);
                *(short8*)&As[row * 64 + ((lane & 7) ^ srow) * 8] = w;
            }
        } else {
#pragma unroll
            for (int c = 0; c < BM / 32; ++c)
                stage16(Ab + k0 + (size_t)(8 * c) * K, ldsA + c * 512);
        }
#pragma unroll
        for (int c = 0; c < BN / 32; ++c)
            stage16(Bb + k0 + (size_t)(8 * c) * K, ldsB + c * 512);
        __syncthreads();  // vmcnt + lgkm drain: tile visible
#pragma unroll
        for (int ch = 0; ch < 2; ++ch) {
            int sw = ch ? sw1 : sw0;
            short8 af[WM / 16], bf[NBF];
#pragma unroll
            for (int i = 0; i < WM / 16; ++i)
                af[i] = *(const short8*)&As[(wm + 16 * i + lo) * 64 + sw];
#pragma unroll
            for (int j = 0; j < NBF; ++j)
                bf[j] = *(const short8*)&Bs[(wn + 16 * j + lo) * 64 + sw];
#pragma unroll
            for (int i = 0; i < WM / 16; ++i)
#pragma unroll
                for (int j = 0; j < NBF; ++j)
                    acc[i][j] = __builtin_amdgcn_mfma_f32_16x16x32_bf16(af[i], bf[j], acc[i][j], 0, 0, 0);
        }
        __syncthreads();  // all reads done before next stage overwrites
    }

    if (MODE == 0) {
        int ncb = n0 + wn;
        int which = ncb / 768;  // wave-uniform: WN | 768
        if (which == 2) {       // V^T: packed 8B stores (regs = consecutive s)
#pragma unroll
            for (int i = 0; i < WM / 16; ++i) {
                int mrow = m0 + wm + 16 * i + 4 * hi;
                int b = mrow >> 10, s0 = mrow & 1023;
#pragma unroll
                for (int j = 0; j < NBF; ++j) {
                    int nc = (ncb % 768) + 16 * j;
                    int h = nc >> 6, d0 = nc & 63;
                    size_t bh = (size_t)(b * 12 + h);
                    uint2 pk;
                    pk.x = pack2bf(acc[i][j][0], acc[i][j][1]);
                    pk.y = pack2bf(acc[i][j][2], acc[i][j][3]);
                    *(uint2*)&v[(bh * 64 + d0 + lo) * 1024 + s0] = pk;
                }
            }
        } else {  // q/k: scalar stores, lanes contiguous in d (32B runs/instr)
            u16* dst = (which == 0) ? q : kk;
            float scale = (which == 0) ? 0.18033688f : 1.0f;  // 1/8 * log2(e)
#pragma unroll
            for (int i = 0; i < WM / 16; ++i) {
#pragma unroll
                for (int r = 0; r < 4; ++r) {
                    int mrow = m0 + wm + 16 * i + 4 * hi + r;
                    int b = mrow >> 10, s = mrow & 1023;
#pragma unroll
                    for (int j = 0; j < NBF; ++j) {
                        int nc = (ncb % 768) + 16 * j;
                        int h = nc >> 6, d0 = nc & 63;
                        size_t bh = (size_t)(b * 12 + h);
                        dst[(bh * 1024 + s) * 64 + d0 + lo] = f2bf(acc[i][j][r] * scale);
                    }
                }
            }
        }
    } else {  // fp32 out: lanes contiguous in n (64B runs/instr)
#pragma unroll
        for (int i = 0; i < WM / 16; ++i)
#pragma unroll
            for (int j = 0; j < NBF; ++j)
#pragma unroll
                for (int r = 0; r < 4; ++r) {
                    int mrow = m0 + wm + 16 * i + 4 * hi + r;
                    int ncol = n0 + wn + 16 * j + lo;
                    outf[(size_t)mrow * 768 + ncol] = acc[i][j][r];
                }
    }
}

// ---------- flash attention v10 (r19 known-good): single-buffer LDS, 6 blocks/CU, LPT ----------
__global__ __launch_bounds__(256) void attn_fwd(const u16* __restrict__ qg,
                                                const u16* __restrict__ kg,
                                                const u16* __restrict__ vg,
                                                u16* __restrict__ ab) {
    __shared__ __align__(16) u16 Kl[64 * 64];
    __shared__ __align__(16) u16 Vl[64 * 64];
    __shared__ __align__(16) u16 P[4][16][72];
    int tid = threadIdx.x, wave = tid >> 6, lane = tid & 63;
    int lo = lane & 15, hi = lane >> 4;
    int bid = blockIdx.x;
    int xcd = bid & 7;
    int idx = bid >> 3;              // 0..191 within XCD
    int qblk = 15 - (idx / 12);      // long blocks dispatch first (LPT)
    int bh = xcd * 12 + (idx % 12);  // same-head blocks share an XCD
    int b = bh / 12, h = bh % 12;
    u16(*Pw)[72] = P[wave];
    int srow = lane >> 3;
    int schunk = (lane & 7) ^ srow;
    const u16* kA = kg + ((size_t)bh << 16) + (size_t)(16 * wave + srow) * 64 + schunk * 8;
    const u16* vA = vg + ((size_t)bh << 16) + (size_t)(16 * wave + srow) * 1024 + schunk * 8;
    int sw0 = (hi ^ (lo & 7)) * 8;
    int sw1 = ((4 + hi) ^ (lo & 7)) * 8;

    auto stageKV = [&](int kv0) {
        u16* kD = Kl + wave * 1024;
        u16* vD = Vl + wave * 1024;
        stage16(kA + (size_t)kv0 * 64, kD);
        stage16(kA + (size_t)kv0 * 64 + 512, kD + 512);
        stage16(vA + kv0, vD);
        stage16(vA + kv0 + 8 * 1024, vD + 512);
    };

    int q0 = qblk * 64 + 16 * wave;
    const u16* qrow = qg + ((size_t)bh * 1024 + q0 + lo) * 64 + hi * 8;
    short8 qf0 = *(const short8*)qrow;
    short8 qf1 = *(const short8*)(qrow + 32);
    f32x4 acc[4] = {};
    float lsum = 0.f;
    int nt = qblk + 1;
#pragma unroll 1
    for (int t = 0; t < nt; ++t) {
        int kv0 = t * 64;
        stageKV(kv0);
        __syncthreads();  // stage drain (hidden by co-resident blocks)
        f32x4 st[4] = {};
        __builtin_amdgcn_s_setprio(1);
#pragma unroll
        for (int f = 0; f < 4; ++f) {
            const u16* kp = &Kl[(16 * f + lo) * 64];
            short8 k0 = *(const short8*)(kp + sw0);
            short8 k1 = *(const short8*)(kp + sw1);
            st[f] = __builtin_amdgcn_mfma_f32_16x16x32_bf16(k0, qf0, st[f], 0, 0, 0);
            st[f] = __builtin_amdgcn_mfma_f32_16x16x32_bf16(k1, qf1, st[f], 0, 0, 0);
        }
        __builtin_amdgcn_s_setprio(0);
        if (t == nt - 1) {  // causal mask on diagonal tile
#pragma unroll
            for (int f = 0; f < 4; ++f) {
                int kvb = kv0 + 16 * f + 4 * hi;
#pragma unroll
                for (int r = 0; r < 4; ++r)
                    if (kvb + r > q0 + lo) st[f][r] = -1e30f;
            }
        }
#pragma unroll
        for (int f = 0; f < 4; ++f) {
            float p0 = exp2f(st[f][0]);
            float p1 = exp2f(st[f][1]);
            float p2 = exp2f(st[f][2]);
            float p3 = exp2f(st[f][3]);
            lsum += (p0 + p1) + (p2 + p3);
            uint2 wv;
            wv.x = pack2bf(p0, p1);
            wv.y = pack2bf(p2, p3);
            *(uint2*)&Pw[lo][16 * f + 4 * hi] = wv;  // P^T[q=lo][kv]
        }
        asm volatile("s_waitcnt lgkmcnt(0)" ::: "memory");  // cross-lane P order
        __builtin_amdgcn_s_setprio(1);
#pragma unroll
        for (int c = 0; c < 2; ++c) {
            short8 pb = *(const short8*)&Pw[lo][c * 32 + hi * 8];
            int sw = c ? sw1 : sw0;
#pragma unroll
            for (int f2 = 0; f2 < 4; ++f2) {
                short8 vf = *(const short8*)(&Vl[(16 * f2 + lo) * 64] + sw);
                acc[f2] = __builtin_amdgcn_mfma_f32_16x16x32_bf16(vf, pb, acc[f2], 0, 0, 0);
            }
        }
        __builtin_amdgcn_s_setprio(0);
        __syncthreads();  // all reads done before next stage overwrites
    }
    lsum += __shfl_xor(lsum, 16);
    lsum += __shfl_xor(lsum, 32);
    float inv = 1.0f / lsum;
    u16* orow = ab + ((size_t)b * 1024 + q0 + lo) * 768 + h * 64 + 4 * hi;
#pragma unroll
    for (int f2 = 0; f2 < 4; ++f2) {
        uint2 wv;
        wv.x = pack2bf(acc[f2][0] * inv, acc[f2][1] * inv);
        wv.y = pack2bf(acc[f2][2] * inv, acc[f2][3] * inv);
        *(uint2*)(orow + 16 * f2) = wv;
    }
}

extern "C" void kernel_launch(void* const* d_in, const int* in_sizes, int n_in,
                              void* d_out, int out_size, void* d_ws, size_t ws_size,
                              hipStream_t stream) {
    const float* x = (const float*)d_in[0];
    const float* Wa = (const float*)d_in[1];
    const float* Wp = (const float*)d_in[2];
    float* out = (float*)d_out;
    char* ws = (char*)d_ws;
    const size_t SZ = (size_t)8 * 1024 * 768 * 2;  // one bf16 tensor
    u16* qb = (u16*)(ws + SZ);                     // [b,h,s,d] scaled by 1/8*log2e
    u16* kb = (u16*)(ws + 2 * SZ);                 // [b,h,s,d]
    u16* vb = (u16*)(ws + 3 * SZ);                 // [b,h,d,s] (transposed)
    u16* ab = (u16*)(ws + 4 * SZ);                 // attn out bf16 [8192][768]
    u16* wat = (u16*)(ws + 5 * SZ);                // W_attn^T bf16 [2304][768]
    u16* wpt = (u16*)(ws + 5 * SZ + (size_t)2304 * 768 * 2);  // W_proj^T bf16 [768][768]

    prep<<<576, 256, 0, stream>>>(Wa, Wp, wat, wpt);
    gemmT<0, 64, 96, 3><<<768, 256, 0, stream>>>(x, nullptr, wat, qb, kb, vb, nullptr, 12);  // 128x192, fp32-A fused
    attn_fwd<<<1536, 256, 0, stream>>>(qb, kb, vb, ab);
    gemmT<1, 32, 64, 4><<<768, 256, 0, stream>>>(nullptr, ab, wpt, nullptr, nullptr, nullptr, out, 6);  // 64x128
}

// Round 21
// 92.009 us; speedup vs baseline: 1.0303x; 1.0303x over previous
//
#include <hip/hip_runtime.h>
#include <hip/hip_bf16.h>

typedef __attribute__((ext_vector_type(4))) float f32x4;
typedef __attribute__((ext_vector_type(8))) short short8;
typedef unsigned short u16;
typedef unsigned int u32;

__device__ __forceinline__ u16 f2bf(float f) {
    u32 u = __float_as_uint(f);
    u32 r = (u + 0x7fffu + ((u >> 16) & 1u)) >> 16;
    return (u16)r;
}
__device__ __forceinline__ u32 pack2bf(float a, float b) {
    __hip_bfloat162 w = __float22bfloat162_rn(float2{a, b});
    return *(u32*)&w;
}
__device__ __forceinline__ void stage16(const u16* gsrc, u16* ldsdst) {
    __builtin_amdgcn_global_load_lds((const __attribute__((address_space(1))) void*)gsrc,
                                     (__attribute__((address_space(3))) void*)ldsdst, 16, 0, 0);
}

// ---------- fused prep: W_attn^T + W_proj^T (fp32->bf16) + x->bf16 ----------
// r20 lesson: keep x-conversion here (bandwidth-bound, full TLP); fusing it
// into the GEMM's reg-staging path put cvt+ds_write on the critical path (+8us).
__global__ __launch_bounds__(256) void prep(const float* __restrict__ x,
                                            const float* __restrict__ Wa,
                                            const float* __restrict__ Wp,
                                            u16* __restrict__ xb, u16* __restrict__ wat,
                                            u16* __restrict__ wpt) {
    __shared__ float tile[64][65];
    int blk = blockIdx.x;
    if (blk < 576) {
        const float* W;
        u16* Wt;
        int N, bx, by;
        if (blk < 432) {
            W = Wa; Wt = wat; N = 2304; bx = blk % 36; by = blk / 36;
        } else {
            int i = blk - 432;
            W = Wp; Wt = wpt; N = 768; bx = i % 12; by = i / 12;
        }
        int n0 = bx * 64, k0 = by * 64;
        int c = threadIdx.x & 63, r0 = threadIdx.x >> 6;
#pragma unroll
        for (int i = 0; i < 16; ++i) {
            int r = r0 * 16 + i;
            tile[r][c] = W[(size_t)(k0 + r) * N + n0 + c];
        }
        __syncthreads();
#pragma unroll
        for (int i = 0; i < 16; ++i) {
            int r = r0 * 16 + i;
            Wt[(size_t)(n0 + r) * 768 + k0 + c] = f2bf(tile[c][r]);
        }
    } else {
        const int n4 = (8 * 1024 * 768) / 4;
        int i = (blk - 576) * 256 + threadIdx.x;
        int stride = 1024 * 256;
        for (; i < n4; i += stride) {
            float4 v = ((const float4*)x)[i];
            ushort4 o;
            o.x = f2bf(v.x); o.y = f2bf(v.y); o.z = f2bf(v.z); o.w = f2bf(v.w);
            ((ushort4*)xb)[i] = o;
        }
    }
}

// ---------- bf16 GEMM: BK=64 single-buffer, XOR-swizzled LDS, tileable BN ----------
// (r16/r19 known-good: MODE 0 = 128x192 grid 768 = 3/CU exact; MODE 1 = 64x128.)
template <int MODE, int WM, int WN, int WPE>
__global__ __launch_bounds__(256, WPE) void gemmT(const u16* __restrict__ A,
                                                  const u16* __restrict__ Bt,
                                                  u16* __restrict__ q, u16* __restrict__ kk,
                                                  u16* __restrict__ v, float* __restrict__ outf,
                                                  int nby) {
    const int K = 768;
    const int BM = 2 * WM;
    const int BN = 2 * WN;
    const int NBF = WN / 16;
    __shared__ __align__(16) u16 As[BM * 64];
    __shared__ __align__(16) u16 Bs[BN * 64];
    int nwg = gridDim.x;
    int bid = blockIdx.x;
    int wgid = (bid & 7) * (nwg >> 3) + (bid >> 3);  // XCD-contiguous
    int mb = wgid / nby, nb = wgid % nby;
    int m0 = mb * BM, n0 = nb * BN;
    int tid = threadIdx.x;
    int wave = tid >> 6, lane = tid & 63;
    int lo = lane & 15, hi = lane >> 4;
    int wm = (wave >> 1) * WM, wn = (wave & 1) * WN;
    int srow = lane >> 3;            // 0..7 within 8-row stage chunk
    int schunk = (lane & 7) ^ srow;  // pre-swizzled source chunk (row&7 == srow)
    int sw0 = (hi ^ (lo & 7)) * 8;        // ds_read swizzle, k-chunk 0
    int sw1 = ((4 + hi) ^ (lo & 7)) * 8;  // k-chunk 1
    f32x4 acc[WM / 16][NBF] = {};
    const u16* Ab = A + (size_t)(m0 + (BM / 4) * wave + srow) * K + schunk * 8;
    const u16* Bb = Bt + (size_t)(n0 + (BN / 4) * wave + srow) * K + schunk * 8;
    u16* ldsA = &As[((BM / 4) * wave) * 64];
    u16* ldsB = &Bs[((BN / 4) * wave) * 64];

    for (int k0 = 0; k0 < K; k0 += 64) {
#pragma unroll
        for (int c = 0; c < BM / 32; ++c)
            stage16(Ab + k0 + (size_t)(8 * c) * K, ldsA + c * 512);
#pragma unroll
        for (int c = 0; c < BN / 32; ++c)
            stage16(Bb + k0 + (size_t)(8 * c) * K, ldsB + c * 512);
        __syncthreads();  // vmcnt drain: tile visible
#pragma unroll
        for (int ch = 0; ch < 2; ++ch) {
            int sw = ch ? sw1 : sw0;
            short8 af[WM / 16], bf[NBF];
#pragma unroll
            for (int i = 0; i < WM / 16; ++i)
                af[i] = *(const short8*)&As[(wm + 16 * i + lo) * 64 + sw];
#pragma unroll
            for (int j = 0; j < NBF; ++j)
                bf[j] = *(const short8*)&Bs[(wn + 16 * j + lo) * 64 + sw];
#pragma unroll
            for (int i = 0; i < WM / 16; ++i)
#pragma unroll
                for (int j = 0; j < NBF; ++j)
                    acc[i][j] = __builtin_amdgcn_mfma_f32_16x16x32_bf16(af[i], bf[j], acc[i][j], 0, 0, 0);
        }
        __syncthreads();  // all reads done before next stage overwrites
    }

    if (MODE == 0) {
        int ncb = n0 + wn;
        int which = ncb / 768;  // wave-uniform: WN | 768
        if (which == 2) {       // V^T: packed 8B stores (regs = consecutive s)
#pragma unroll
            for (int i = 0; i < WM / 16; ++i) {
                int mrow = m0 + wm + 16 * i + 4 * hi;
                int b = mrow >> 10, s0 = mrow & 1023;
#pragma unroll
                for (int j = 0; j < NBF; ++j) {
                    int nc = (ncb % 768) + 16 * j;
                    int h = nc >> 6, d0 = nc & 63;
                    size_t bh = (size_t)(b * 12 + h);
                    uint2 pk;
                    pk.x = pack2bf(acc[i][j][0], acc[i][j][1]);
                    pk.y = pack2bf(acc[i][j][2], acc[i][j][3]);
                    *(uint2*)&v[(bh * 64 + d0 + lo) * 1024 + s0] = pk;
                }
            }
        } else {  // q/k: scalar stores, lanes contiguous in d (32B runs/instr)
            u16* dst = (which == 0) ? q : kk;
            float scale = (which == 0) ? 0.18033688f : 1.0f;  // 1/8 * log2(e)
#pragma unroll
            for (int i = 0; i < WM / 16; ++i) {
#pragma unroll
                for (int r = 0; r < 4; ++r) {
                    int mrow = m0 + wm + 16 * i + 4 * hi + r;
                    int b = mrow >> 10, s = mrow & 1023;
#pragma unroll
                    for (int j = 0; j < NBF; ++j) {
                        int nc = (ncb % 768) + 16 * j;
                        int h = nc >> 6, d0 = nc & 63;
                        size_t bh = (size_t)(b * 12 + h);
                        dst[(bh * 1024 + s) * 64 + d0 + lo] = f2bf(acc[i][j][r] * scale);
                    }
                }
            }
        }
    } else {  // fp32 out: lanes contiguous in n (64B runs/instr)
#pragma unroll
        for (int i = 0; i < WM / 16; ++i)
#pragma unroll
            for (int j = 0; j < NBF; ++j)
#pragma unroll
                for (int r = 0; r < 4; ++r) {
                    int mrow = m0 + wm + 16 * i + 4 * hi + r;
                    int ncol = n0 + wn + 16 * j + lo;
                    outf[(size_t)mrow * 768 + ncol] = acc[i][j][r];
                }
    }
}

// ---------- flash attention v10 (r19 known-good): single-buffer LDS, 6 blocks/CU, LPT ----------
__global__ __launch_bounds__(256) void attn_fwd(const u16* __restrict__ qg,
                                                const u16* __restrict__ kg,
                                                const u16* __restrict__ vg,
                                                u16* __restrict__ ab) {
    __shared__ __align__(16) u16 Kl[64 * 64];
    __shared__ __align__(16) u16 Vl[64 * 64];
    __shared__ __align__(16) u16 P[4][16][72];
    int tid = threadIdx.x, wave = tid >> 6, lane = tid & 63;
    int lo = lane & 15, hi = lane >> 4;
    int bid = blockIdx.x;
    int xcd = bid & 7;
    int idx = bid >> 3;              // 0..191 within XCD
    int qblk = 15 - (idx / 12);      // long blocks dispatch first (LPT)
    int bh = xcd * 12 + (idx % 12);  // same-head blocks share an XCD
    int b = bh / 12, h = bh % 12;
    u16(*Pw)[72] = P[wave];
    int srow = lane >> 3;
    int schunk = (lane & 7) ^ srow;
    const u16* kA = kg + ((size_t)bh << 16) + (size_t)(16 * wave + srow) * 64 + schunk * 8;
    const u16* vA = vg + ((size_t)bh << 16) + (size_t)(16 * wave + srow) * 1024 + schunk * 8;
    int sw0 = (hi ^ (lo & 7)) * 8;
    int sw1 = ((4 + hi) ^ (lo & 7)) * 8;

    auto stageKV = [&](int kv0) {
        u16* kD = Kl + wave * 1024;
        u16* vD = Vl + wave * 1024;
        stage16(kA + (size_t)kv0 * 64, kD);
        stage16(kA + (size_t)kv0 * 64 + 512, kD + 512);
        stage16(vA + kv0, vD);
        stage16(vA + kv0 + 8 * 1024, vD + 512);
    };

    int q0 = qblk * 64 + 16 * wave;
    const u16* qrow = qg + ((size_t)bh * 1024 + q0 + lo) * 64 + hi * 8;
    short8 qf0 = *(const short8*)qrow;
    short8 qf1 = *(const short8*)(qrow + 32);
    f32x4 acc[4] = {};
    float lsum = 0.f;
    int nt = qblk + 1;
#pragma unroll 1
    for (int t = 0; t < nt; ++t) {
        int kv0 = t * 64;
        stageKV(kv0);
        __syncthreads();  // stage drain (hidden by co-resident blocks)
        f32x4 st[4] = {};
        __builtin_amdgcn_s_setprio(1);
#pragma unroll
        for (int f = 0; f < 4; ++f) {
            const u16* kp = &Kl[(16 * f + lo) * 64];
            short8 k0 = *(const short8*)(kp + sw0);
            short8 k1 = *(const short8*)(kp + sw1);
            st[f] = __builtin_amdgcn_mfma_f32_16x16x32_bf16(k0, qf0, st[f], 0, 0, 0);
            st[f] = __builtin_amdgcn_mfma_f32_16x16x32_bf16(k1, qf1, st[f], 0, 0, 0);
        }
        __builtin_amdgcn_s_setprio(0);
        if (t == nt - 1) {  // causal mask on diagonal tile
#pragma unroll
            for (int f = 0; f < 4; ++f) {
                int kvb = kv0 + 16 * f + 4 * hi;
#pragma unroll
                for (int r = 0; r < 4; ++r)
                    if (kvb + r > q0 + lo) st[f][r] = -1e30f;
            }
        }
#pragma unroll
        for (int f = 0; f < 4; ++f) {
            float p0 = exp2f(st[f][0]);
            float p1 = exp2f(st[f][1]);
            float p2 = exp2f(st[f][2]);
            float p3 = exp2f(st[f][3]);
            lsum += (p0 + p1) + (p2 + p3);
            uint2 wv;
            wv.x = pack2bf(p0, p1);
            wv.y = pack2bf(p2, p3);
            *(uint2*)&Pw[lo][16 * f + 4 * hi] = wv;  // P^T[q=lo][kv]
        }
        asm volatile("s_waitcnt lgkmcnt(0)" ::: "memory");  // cross-lane P order
        __builtin_amdgcn_s_setprio(1);
#pragma unroll
        for (int c = 0; c < 2; ++c) {
            short8 pb = *(const short8*)&Pw[lo][c * 32 + hi * 8];
            int sw = c ? sw1 : sw0;
#pragma unroll
            for (int f2 = 0; f2 < 4; ++f2) {
                short8 vf = *(const short8*)(&Vl[(16 * f2 + lo) * 64] + sw);
                acc[f2] = __builtin_amdgcn_mfma_f32_16x16x32_bf16(vf, pb, acc[f2], 0, 0, 0);
            }
        }
        __builtin_amdgcn_s_setprio(0);
        __syncthreads();  // all reads done before next stage overwrites
    }
    lsum += __shfl_xor(lsum, 16);
    lsum += __shfl_xor(lsum, 32);
    float inv = 1.0f / lsum;
    u16* orow = ab + ((size_t)b * 1024 + q0 + lo) * 768 + h * 64 + 4 * hi;
#pragma unroll
    for (int f2 = 0; f2 < 4; ++f2) {
        uint2 wv;
        wv.x = pack2bf(acc[f2][0] * inv, acc[f2][1] * inv);
        wv.y = pack2bf(acc[f2][2] * inv, acc[f2][3] * inv);
        *(uint2*)(orow + 16 * f2) = wv;
    }
}

extern "C" void kernel_launch(void* const* d_in, const int* in_sizes, int n_in,
                              void* d_out, int out_size, void* d_ws, size_t ws_size,
                              hipStream_t stream) {
    const float* x = (const float*)d_in[0];
    const float* Wa = (const float*)d_in[1];
    const float* Wp = (const float*)d_in[2];
    float* out = (float*)d_out;
    char* ws = (char*)d_ws;
    const size_t SZ = (size_t)8 * 1024 * 768 * 2;  // one bf16 tensor
    u16* xb = (u16*)ws;                            // x bf16 [8192][768]
    u16* qb = (u16*)(ws + SZ);                     // [b,h,s,d] scaled by 1/8*log2e
    u16* kb = (u16*)(ws + 2 * SZ);                 // [b,h,s,d]
    u16* vb = (u16*)(ws + 3 * SZ);                 // [b,h,d,s] (transposed)
    u16* ab = (u16*)(ws + 4 * SZ);                 // attn out bf16 [8192][768]
    u16* wat = (u16*)(ws + 5 * SZ);                // W_attn^T bf16 [2304][768]
    u16* wpt = (u16*)(ws + 5 * SZ + (size_t)2304 * 768 * 2);  // W_proj^T bf16 [768][768]

    prep<<<1600, 256, 0, stream>>>(x, Wa, Wp, xb, wat, wpt);
    gemmT<0, 64, 96, 3><<<768, 256, 0, stream>>>(xb, wat, qb, kb, vb, nullptr, 12);  // 128x192
    attn_fwd<<<1536, 256, 0, stream>>>(qb, kb, vb, ab);
    gemmT<1, 32, 64, 4><<<768, 256, 0, stream>>>(ab, wpt, nullptr, nullptr, nullptr, out, 6);  // 64x128
}